// Round 1
// baseline (1889.392 us; speedup 1.0000x reference)
//
#include <hip/hip_runtime.h>

#define Tn      8192
#define Cn      1024
#define En      8
#define Fn      2752
#define MAXROWS 17408
#define BM 128
#define BN 128
#define BK 32
#define LDA 40
#define LDB 40

typedef __bf16 bf16;
typedef bf16  bf16x8 __attribute__((ext_vector_type(8)));
typedef bf16  bf16x4 __attribute__((ext_vector_type(4)));
typedef float f32x4  __attribute__((ext_vector_type(4)));

// ---------------- gating: logits -> softmax -> top2 -> normalized weights ----
__global__ __launch_bounds__(256) void gate_kernel(
    const float* __restrict__ x, const float* __restrict__ wgate,
    int* __restrict__ topk_i, float* __restrict__ topk_w, int* __restrict__ counts)
{
  int lane = threadIdx.x & 63;
  int wid  = threadIdx.x >> 6;
  int t = blockIdx.x * 4 + wid;
  const float* xr = x + (size_t)t * Cn;
  float acc[En];
#pragma unroll
  for (int e = 0; e < En; ++e) acc[e] = 0.f;
  for (int c = lane; c < Cn; c += 64) {
    float xv = xr[c];
#pragma unroll
    for (int e = 0; e < En; ++e) acc[e] = fmaf(xv, wgate[e * Cn + c], acc[e]);
  }
#pragma unroll
  for (int e = 0; e < En; ++e) {
#pragma unroll
    for (int o = 32; o > 0; o >>= 1) acc[e] += __shfl_xor(acc[e], o, 64);
  }
  if (lane == 0) {
    float mx = acc[0];
#pragma unroll
    for (int e = 1; e < En; ++e) mx = fmaxf(mx, acc[e]);
    float p[En], Z = 0.f;
#pragma unroll
    for (int e = 0; e < En; ++e) { p[e] = __expf(acc[e] - mx); Z += p[e]; }
    int i0 = 0;
#pragma unroll
    for (int e = 1; e < En; ++e) if (p[e] > p[i0]) i0 = e;
    int i1 = (i0 == 0) ? 1 : 0;
#pragma unroll
    for (int e = 0; e < En; ++e) if (e != i0 && p[e] > p[i1]) i1 = e;
    float s0 = p[i0] / Z, s1 = p[i1] / Z;
    float inv = 1.f / (s0 + s1 + 1e-9f);
    topk_i[2 * t] = i0;       topk_i[2 * t + 1] = i1;
    topk_w[2 * t] = s0 * inv; topk_w[2 * t + 1] = s1 * inv;
    atomicAdd(&counts[i0], 1);
    atomicAdd(&counts[i1], 1);
  }
}

// ---------------- per-expert 128-aligned offsets -----------------------------
__global__ void offsets_kernel(const int* __restrict__ counts,
                               int* __restrict__ fill, int* __restrict__ off)
{
  if (threadIdx.x == 0 && blockIdx.x == 0) {
    int o = 0;
    for (int e = 0; e < En; ++e) {
      off[e]  = o;
      fill[e] = o;
      o += (counts[e] + BM - 1) & ~(BM - 1);
    }
    off[En] = o;  // padded_total (multiple of 128)
  }
}

// ---------------- scatter tokens into per-expert contiguous row lists --------
__global__ __launch_bounds__(256) void scatter_kernel(
    const int* __restrict__ topk_i, const float* __restrict__ topk_w,
    int* __restrict__ fill, int* __restrict__ tok_list, float* __restrict__ wgt_list)
{
  int t = blockIdx.x * 256 + threadIdx.x;
#pragma unroll
  for (int j = 0; j < 2; ++j) {
    int e = topk_i[2 * t + j];
    int pos = atomicAdd(&fill[e], 1);
    tok_list[pos] = t;
    wgt_list[pos] = topk_w[2 * t + j];
  }
}

// ---------------- weight transpose + fp32->bf16 ------------------------------
// src: [z][M][N] fp32 row-major  ->  dst: [z][N][M] bf16 row-major (k-contiguous B^T)
__global__ __launch_bounds__(256) void transpose_cvt(
    const float* __restrict__ src, bf16* __restrict__ dst, int M, int N)
{
  __shared__ float tile[32][33];
  src += (size_t)blockIdx.z * M * N;
  dst += (size_t)blockIdx.z * M * N;
  int bm = blockIdx.x * 32;
  int bn = blockIdx.y * 32;
  int t = threadIdx.x;
#pragma unroll
  for (int p = 0; p < 4; ++p) {
    int idx = p * 256 + t;
    int r = idx >> 5, c = idx & 31;
    tile[r][c] = src[(size_t)(bm + r) * N + bn + c];
  }
  __syncthreads();
  int r = t >> 3, c0 = (t & 7) * 4;
  bf16x4 v;
#pragma unroll
  for (int i = 0; i < 4; ++i) v[i] = (bf16)tile[c0 + i][r];
  *(bf16x4*)(dst + (size_t)(bn + r) * M + bm + c0) = v;
}

// ---------------- GEMM1: h = wgt * silu(x@wg) * (x@wu), bf16 out -------------
__global__ __launch_bounds__(256) void gemm1_kernel(
    const float* __restrict__ x, const bf16* __restrict__ wgT, const bf16* __restrict__ wuT,
    const int* __restrict__ off, const int* __restrict__ counts,
    const int* __restrict__ tok_list, const float* __restrict__ wgt_list,
    bf16* __restrict__ h, int row_lo)
{
  int m0 = row_lo + blockIdx.x * BM;
  if (m0 >= off[En]) return;
  int e = 0;
  while (off[e + 1] <= m0) ++e;
  const int base = off[e], cnt = counts[e];
  const int n0 = blockIdx.y * BN;

  __shared__ bf16 As[BM * LDA];
  __shared__ bf16 Bg[BN * LDB];
  __shared__ bf16 Bu[BN * LDB];

  const int tid = threadIdx.x;
  const int lane = tid & 63, wid = tid >> 6;
  const int wm = (wid >> 1) * 64, wn = (wid & 1) * 64;

  f32x4 zero4; zero4[0] = 0.f; zero4[1] = 0.f; zero4[2] = 0.f; zero4[3] = 0.f;
  f32x4 accg[4][4], accu[4][4];
#pragma unroll
  for (int i = 0; i < 4; ++i)
#pragma unroll
    for (int j = 0; j < 4; ++j) { accg[i][j] = zero4; accu[i][j] = zero4; }

  const bf16* wge = wgT + (size_t)e * Fn * Cn;
  const bf16* wue = wuT + (size_t)e * Fn * Cn;

  for (int kt = 0; kt < Cn / BK; ++kt) {
    __syncthreads();
    // A: gather x rows (fp32 -> bf16)
#pragma unroll
    for (int p = 0; p < 4; ++p) {
      int idx = p * 256 + tid;
      int row = idx >> 3, seg = idx & 7;
      int grow = m0 + row;
      float4 v = make_float4(0.f, 0.f, 0.f, 0.f);
      if (grow - base < cnt) {
        int tok = tok_list[grow];
        v = *(const float4*)(x + (size_t)tok * Cn + kt * BK + seg * 4);
      }
      bf16x4 pv;
      pv[0] = (bf16)v.x; pv[1] = (bf16)v.y; pv[2] = (bf16)v.z; pv[3] = (bf16)v.w;
      *(bf16x4*)(As + row * LDA + seg * 4) = pv;
    }
    // B: pre-transposed bf16, straight 16B copies
#pragma unroll
    for (int p = 0; p < 2; ++p) {
      int idx = p * 256 + tid;
      int nr = idx >> 2, seg = idx & 3;
      int f = n0 + nr;
      bf16x8 vg = {}, vu = {};
      if (f < Fn) {
        size_t oo = (size_t)f * Cn + kt * BK + seg * 8;
        vg = *(const bf16x8*)(wge + oo);
        vu = *(const bf16x8*)(wue + oo);
      }
      *(bf16x8*)(Bg + nr * LDB + seg * 8) = vg;
      *(bf16x8*)(Bu + nr * LDB + seg * 8) = vu;
    }
    __syncthreads();

    bf16x8 a[4], bg[4], bu[4];
    const int fr = lane & 15, kq = (lane >> 4) * 8;
#pragma unroll
    for (int mi = 0; mi < 4; ++mi)
      a[mi] = *(const bf16x8*)(As + (wm + mi * 16 + fr) * LDA + kq);
#pragma unroll
    for (int ni = 0; ni < 4; ++ni) {
      bg[ni] = *(const bf16x8*)(Bg + (wn + ni * 16 + fr) * LDB + kq);
      bu[ni] = *(const bf16x8*)(Bu + (wn + ni * 16 + fr) * LDB + kq);
    }
#pragma unroll
    for (int mi = 0; mi < 4; ++mi)
#pragma unroll
      for (int ni = 0; ni < 4; ++ni) {
        accg[mi][ni] = __builtin_amdgcn_mfma_f32_16x16x32_bf16(a[mi], bg[ni], accg[mi][ni], 0, 0, 0);
        accu[mi][ni] = __builtin_amdgcn_mfma_f32_16x16x32_bf16(a[mi], bu[ni], accu[mi][ni], 0, 0, 0);
      }
  }

  // epilogue: h = w * silu(g) * u   (C/D layout: col=lane&15, row=(lane>>4)*4+reg)
  const int rq = (lane >> 4) * 4, cl = lane & 15;
#pragma unroll
  for (int mi = 0; mi < 4; ++mi) {
#pragma unroll
    for (int r = 0; r < 4; ++r) {
      int grow = m0 + wm + mi * 16 + rq + r;
      if (grow - base >= cnt) continue;
      float w = wgt_list[grow];
      bf16* hr = h + (size_t)(grow - row_lo) * Fn;
#pragma unroll
      for (int ni = 0; ni < 4; ++ni) {
        int f = n0 + wn + ni * 16 + cl;
        if (f >= Fn) continue;
        float g = accg[mi][ni][r], u = accu[mi][ni][r];
        float hv = w * u * (g / (1.f + __expf(-g)));
        hr[f] = (bf16)hv;
      }
    }
  }
}

// ---------------- GEMM2: out[tok] += h @ wd  (atomic combine) ----------------
__global__ __launch_bounds__(256) void gemm2_kernel(
    const bf16* __restrict__ h, const bf16* __restrict__ wdT,
    const int* __restrict__ off, const int* __restrict__ counts,
    const int* __restrict__ tok_list, float* __restrict__ out, int row_lo)
{
  int m0 = row_lo + blockIdx.x * BM;
  if (m0 >= off[En]) return;
  int e = 0;
  while (off[e + 1] <= m0) ++e;
  const int base = off[e], cnt = counts[e];
  const int n0 = blockIdx.y * BN;

  __shared__ bf16 As[BM * LDA];
  __shared__ bf16 Bs[BN * LDB];

  const int tid = threadIdx.x;
  const int lane = tid & 63, wid = tid >> 6;
  const int wm = (wid >> 1) * 64, wn = (wid & 1) * 64;

  f32x4 zero4; zero4[0] = 0.f; zero4[1] = 0.f; zero4[2] = 0.f; zero4[3] = 0.f;
  f32x4 acc[4][4];
#pragma unroll
  for (int i = 0; i < 4; ++i)
#pragma unroll
    for (int j = 0; j < 4; ++j) acc[i][j] = zero4;

  const bf16* wde = wdT + (size_t)e * Cn * Fn;
  const bf16* hb  = h + (size_t)(m0 - row_lo) * Fn;

  for (int kt = 0; kt < Fn / BK; ++kt) {  // 86 iters, exact
    __syncthreads();
#pragma unroll
    for (int p = 0; p < 2; ++p) {
      int idx = p * 256 + tid;
      int row = idx >> 2, seg = idx & 3;
      bf16x8 v = *(const bf16x8*)(hb + (size_t)row * Fn + kt * BK + seg * 8);
      *(bf16x8*)(As + row * LDA + seg * 8) = v;
    }
#pragma unroll
    for (int p = 0; p < 2; ++p) {
      int idx = p * 256 + tid;
      int nr = idx >> 2, seg = idx & 3;
      bf16x8 v = *(const bf16x8*)(wde + (size_t)(n0 + nr) * Fn + kt * BK + seg * 8);
      *(bf16x8*)(Bs + nr * LDB + seg * 8) = v;
    }
    __syncthreads();

    bf16x8 a[4], b[4];
    const int fr = lane & 15, kq = (lane >> 4) * 8;
#pragma unroll
    for (int mi = 0; mi < 4; ++mi)
      a[mi] = *(const bf16x8*)(As + (wm + mi * 16 + fr) * LDA + kq);
#pragma unroll
    for (int ni = 0; ni < 4; ++ni)
      b[ni] = *(const bf16x8*)(Bs + (wn + ni * 16 + fr) * LDB + kq);
#pragma unroll
    for (int mi = 0; mi < 4; ++mi)
#pragma unroll
      for (int ni = 0; ni < 4; ++ni)
        acc[mi][ni] = __builtin_amdgcn_mfma_f32_16x16x32_bf16(a[mi], b[ni], acc[mi][ni], 0, 0, 0);
  }

  const int rq = (lane >> 4) * 4, cl = lane & 15;
#pragma unroll
  for (int mi = 0; mi < 4; ++mi) {
#pragma unroll
    for (int r = 0; r < 4; ++r) {
      int grow = m0 + wm + mi * 16 + rq + r;
      if (grow - base >= cnt) continue;
      int tok = tok_list[grow];
      float* orow = out + (size_t)tok * Cn + n0;
#pragma unroll
      for (int ni = 0; ni < 4; ++ni)
        atomicAdd(orow + wn + ni * 16 + cl, acc[mi][ni][r]);
    }
  }
}

// ---------------- host launch ------------------------------------------------
extern "C" void kernel_launch(void* const* d_in, const int* in_sizes, int n_in,
                              void* d_out, int out_size, void* d_ws, size_t ws_size,
                              hipStream_t stream)
{
  const float* x     = (const float*)d_in[0];
  const float* wgate = (const float*)d_in[1];
  const float* wg    = (const float*)d_in[2];
  const float* wu    = (const float*)d_in[3];
  const float* wd    = (const float*)d_in[4];
  float* out = (float*)d_out;

  char* ws = (char*)d_ws;
  int* counts = (int*)ws;        // 8
  int* fill   = counts + 8;      // 8
  int* off    = fill + 8;        // 9
  size_t o = 256;
  int*   topk_i   = (int*)(ws + o);   o += (size_t)Tn * 2 * 4;
  float* topk_w   = (float*)(ws + o); o += (size_t)Tn * 2 * 4;
  int*   tok_list = (int*)(ws + o);   o += (size_t)MAXROWS * 4;
  float* wgt_list = (float*)(ws + o); o += (size_t)MAXROWS * 4;
  o = (o + 255) & ~(size_t)255;
  const size_t WSZ = (size_t)En * Fn * Cn;  // elements per weight tensor
  bf16* wgT = (bf16*)(ws + o); o += WSZ * 2;
  bf16* wuT = (bf16*)(ws + o); o += WSZ * 2;
  bf16* wdT = (bf16*)(ws + o); o += WSZ * 2;
  bf16* h   = (bf16*)(ws + o);

  size_t havail = ws_size > o ? ws_size - o : 0;
  long crows = (long)(havail / ((size_t)Fn * 2));
  crows &= ~(long)127;
  if (crows > MAXROWS) crows = MAXROWS;
  if (crows < 128) crows = 128;  // below this ws is too small anyway
  const int chunk_rows = (int)crows;
  const int nch = (MAXROWS + chunk_rows - 1) / chunk_rows;

  hipMemsetAsync(counts, 0, 256, stream);
  hipMemsetAsync(d_out, 0, (size_t)out_size * sizeof(float), stream);

  transpose_cvt<<<dim3(Cn / 32, Fn / 32, En), 256, 0, stream>>>(wg, wgT, Cn, Fn);
  transpose_cvt<<<dim3(Cn / 32, Fn / 32, En), 256, 0, stream>>>(wu, wuT, Cn, Fn);
  transpose_cvt<<<dim3(Fn / 32, Cn / 32, En), 256, 0, stream>>>(wd, wdT, Fn, Cn);

  gate_kernel<<<Tn / 4, 256, 0, stream>>>(x, wgate, topk_i, topk_w, counts);
  offsets_kernel<<<1, 64, 0, stream>>>(counts, fill, off);
  scatter_kernel<<<Tn / 256, 256, 0, stream>>>(topk_i, topk_w, fill, tok_list, wgt_list);

  const int mt = chunk_rows / BM;
  for (int c = 0; c < nch; ++c) {
    int row_lo = c * chunk_rows;
    gemm1_kernel<<<dim3(mt, (Fn + BN - 1) / BN), 256, 0, stream>>>(
        x, wgT, wuT, off, counts, tok_list, wgt_list, h, row_lo);
    gemm2_kernel<<<dim3(mt, Cn / BN), 256, 0, stream>>>(
        h, wdT, off, counts, tok_list, out, row_lo);
  }
}

// Round 2
// 1121.032 us; speedup vs baseline: 1.6854x; 1.6854x over previous
//
#include <hip/hip_runtime.h>

#define Tn      8192
#define Cn      1024
#define En      8
#define Fn      2752
#define MAXROWS 17408
#define BM 128
#define BK 32

typedef __bf16 bf16;
typedef bf16  bf16x8 __attribute__((ext_vector_type(8)));
typedef bf16  bf16x4 __attribute__((ext_vector_type(4)));
typedef float f32x4  __attribute__((ext_vector_type(4)));

// async global->LDS, 16B per lane; LDS dest must be wave-uniform base + lane*16
__device__ __forceinline__ void gload16(const bf16* g, bf16* l) {
  __builtin_amdgcn_global_load_lds(
      (const __attribute__((address_space(1))) unsigned int*)g,
      (__attribute__((address_space(3))) unsigned int*)l, 16, 0, 0);
}

// ---------------- gating: logits -> softmax -> top2 -> normalized weights ----
__global__ __launch_bounds__(256) void gate_kernel(
    const float* __restrict__ x, const float* __restrict__ wgate,
    int* __restrict__ topk_i, float* __restrict__ topk_w, int* __restrict__ counts)
{
  int lane = threadIdx.x & 63;
  int wid  = threadIdx.x >> 6;
  int t = blockIdx.x * 4 + wid;
  const float* xr = x + (size_t)t * Cn;
  float acc[En];
#pragma unroll
  for (int e = 0; e < En; ++e) acc[e] = 0.f;
  for (int c = lane; c < Cn; c += 64) {
    float xv = xr[c];
#pragma unroll
    for (int e = 0; e < En; ++e) acc[e] = fmaf(xv, wgate[e * Cn + c], acc[e]);
  }
#pragma unroll
  for (int e = 0; e < En; ++e) {
#pragma unroll
    for (int o = 32; o > 0; o >>= 1) acc[e] += __shfl_xor(acc[e], o, 64);
  }
  if (lane == 0) {
    float mx = acc[0];
#pragma unroll
    for (int e = 1; e < En; ++e) mx = fmaxf(mx, acc[e]);
    float p[En], Z = 0.f;
#pragma unroll
    for (int e = 0; e < En; ++e) { p[e] = __expf(acc[e] - mx); Z += p[e]; }
    int i0 = 0;
#pragma unroll
    for (int e = 1; e < En; ++e) if (p[e] > p[i0]) i0 = e;
    int i1 = (i0 == 0) ? 1 : 0;
#pragma unroll
    for (int e = 0; e < En; ++e) if (e != i0 && p[e] > p[i1]) i1 = e;
    float s0 = p[i0] / Z, s1 = p[i1] / Z;
    float inv = 1.f / (s0 + s1 + 1e-9f);
    topk_i[2 * t] = i0;       topk_i[2 * t + 1] = i1;
    topk_w[2 * t] = s0 * inv; topk_w[2 * t + 1] = s1 * inv;
    atomicAdd(&counts[i0], 1);
    atomicAdd(&counts[i1], 1);
  }
}

// ---------------- per-expert 128-aligned offsets -----------------------------
__global__ void offsets_kernel(const int* __restrict__ counts,
                               int* __restrict__ fill, int* __restrict__ off)
{
  if (threadIdx.x == 0 && blockIdx.x == 0) {
    int o = 0;
    for (int e = 0; e < En; ++e) {
      off[e]  = o;
      fill[e] = o;
      o += (counts[e] + BM - 1) & ~(BM - 1);
    }
    off[En] = o;
  }
}

// ---------------- scatter tokens into per-expert contiguous row lists --------
__global__ __launch_bounds__(256) void scatter_kernel(
    const int* __restrict__ topk_i, const float* __restrict__ topk_w,
    int* __restrict__ fill, int* __restrict__ tok_list, float* __restrict__ wgt_list)
{
  int t = blockIdx.x * 256 + threadIdx.x;
#pragma unroll
  for (int j = 0; j < 2; ++j) {
    int e = topk_i[2 * t + j];
    int pos = atomicAdd(&fill[e], 1);
    tok_list[pos] = t;
    wgt_list[pos] = topk_w[2 * t + j];
  }
}

// ---------------- gather+convert x rows into per-expert order (bf16) ---------
__global__ __launch_bounds__(256) void gather_x(
    const float* __restrict__ x, const int* __restrict__ tok_list, bf16* __restrict__ xg)
{
  int row = blockIdx.x;
  int tok = tok_list[row];
  int c = threadIdx.x * 4;
  float4 v = make_float4(0.f, 0.f, 0.f, 0.f);
  if (tok >= 0) v = *(const float4*)(x + (size_t)tok * Cn + c);
  bf16x4 pv;
  pv[0] = (bf16)v.x; pv[1] = (bf16)v.y; pv[2] = (bf16)v.z; pv[3] = (bf16)v.w;
  *(bf16x4*)(xg + (size_t)row * Cn + c) = pv;
}

// ---------------- weight transpose + fp32->bf16 ------------------------------
// src: [z][M][N] fp32 row-major  ->  dst: [z][N][M] bf16 row-major (k-contiguous)
__global__ __launch_bounds__(256) void transpose_cvt(
    const float* __restrict__ src, bf16* __restrict__ dst, int M, int N)
{
  __shared__ float tile[32][33];
  src += (size_t)blockIdx.z * M * N;
  dst += (size_t)blockIdx.z * M * N;
  int bm = blockIdx.x * 32;
  int bn = blockIdx.y * 32;
  int t = threadIdx.x;
#pragma unroll
  for (int p = 0; p < 4; ++p) {
    int idx = p * 256 + t;
    int r = idx >> 5, c = idx & 31;
    tile[r][c] = src[(size_t)(bm + r) * N + bn + c];
  }
  __syncthreads();
  int r = t >> 3, c0 = (t & 7) * 4;
  bf16x4 v;
#pragma unroll
  for (int i = 0; i < 4; ++i) v[i] = (bf16)tile[c0 + i][r];
  *(bf16x4*)(dst + (size_t)(bn + r) * M + bm + c0) = v;
}

// ---------------- GEMM1: h = wgt * silu(xg@wgT') * (xg@wuT'), bf16 out -------
// block: 128 rows x 64 cols of BOTH gate and up. acc = 64 regs/thread.
__global__ __launch_bounds__(256) void gemm1_kernel(
    const bf16* __restrict__ xg, const bf16* __restrict__ wgT, const bf16* __restrict__ wuT,
    const int* __restrict__ off, const int* __restrict__ counts,
    const float* __restrict__ wgt_list, bf16* __restrict__ h, int row_lo)
{
  const int m0 = row_lo + blockIdx.x * BM;
  if (m0 >= off[En]) return;
  int e = 0;
  while (off[e + 1] <= m0) ++e;
  const int base = off[e], cnt = counts[e];
  const int n0 = blockIdx.y * 64;

  __shared__ bf16 As[BM * BK];   // 128x32 unpadded, row-major (gload layout)
  __shared__ bf16 Bg[64 * BK];
  __shared__ bf16 Bu[64 * BK];

  const int tid = threadIdx.x;
  const int lane = tid & 63, wid = tid >> 6;
  const int wm = (wid >> 1) * 64, wn = (wid & 1) * 32;

  f32x4 z4; z4[0] = 0.f; z4[1] = 0.f; z4[2] = 0.f; z4[3] = 0.f;
  f32x4 accg[4][2], accu[4][2];
#pragma unroll
  for (int i = 0; i < 4; ++i)
#pragma unroll
    for (int j = 0; j < 2; ++j) { accg[i][j] = z4; accu[i][j] = z4; }

  const bf16* wge = wgT + (size_t)e * Fn * Cn;
  const bf16* wue = wuT + (size_t)e * Fn * Cn;

  const int srow = lane >> 2;            // 16 rows per wave-issue
  const int scol = (lane & 3) * 8;       // 4 x 16B segs per 64B row
  const bf16* agp = xg  + (size_t)(m0 + wid * 32 + srow) * Cn + scol;
  const bf16* bgp = wge + (size_t)(n0 + wid * 16 + srow) * Cn + scol;
  const bf16* bup = wue + (size_t)(n0 + wid * 16 + srow) * Cn + scol;
  bf16* alp  = As + wid * 32 * BK + lane * 8;
  bf16* blgp = Bg + wid * 16 * BK + lane * 8;
  bf16* blup = Bu + wid * 16 * BK + lane * 8;

  const int fr = lane & 15, kq = (lane >> 4) * 8;

  for (int kt = 0; kt < Cn / BK; ++kt) {
    __syncthreads();
    gload16(agp, alp);
    gload16(agp + 16 * Cn, alp + 16 * BK);
    gload16(bgp, blgp);
    gload16(bup, blup);
    agp += BK; bgp += BK; bup += BK;
    __syncthreads();

    bf16x8 a[4], bg[2], bu[2];
#pragma unroll
    for (int mi = 0; mi < 4; ++mi)
      a[mi] = *(const bf16x8*)(As + (wm + mi * 16 + fr) * BK + kq);
#pragma unroll
    for (int ni = 0; ni < 2; ++ni) {
      bg[ni] = *(const bf16x8*)(Bg + (wn + ni * 16 + fr) * BK + kq);
      bu[ni] = *(const bf16x8*)(Bu + (wn + ni * 16 + fr) * BK + kq);
    }
#pragma unroll
    for (int mi = 0; mi < 4; ++mi)
#pragma unroll
      for (int ni = 0; ni < 2; ++ni) {
        accg[mi][ni] = __builtin_amdgcn_mfma_f32_16x16x32_bf16(a[mi], bg[ni], accg[mi][ni], 0, 0, 0);
        accu[mi][ni] = __builtin_amdgcn_mfma_f32_16x16x32_bf16(a[mi], bu[ni], accu[mi][ni], 0, 0, 0);
      }
  }

  // epilogue: h = w * silu(g) * u  (C/D: col=lane&15, row=(lane>>4)*4+reg)
  const int rq = (lane >> 4) * 4, cl = lane & 15;
#pragma unroll
  for (int mi = 0; mi < 4; ++mi) {
#pragma unroll
    for (int r = 0; r < 4; ++r) {
      int grow = m0 + wm + mi * 16 + rq + r;
      float w = (grow - base < cnt) ? wgt_list[grow] : 0.f;  // zero pad rows of h
      bf16* hr = h + (size_t)(grow - row_lo) * Fn + n0;
#pragma unroll
      for (int ni = 0; ni < 2; ++ni) {
        float g = accg[mi][ni][r], u = accu[mi][ni][r];
        float hv = w * u * (g / (1.f + __expf(-g)));
        hr[wn + ni * 16 + cl] = (bf16)hv;
      }
    }
  }
}

// ---------------- GEMM2: out[tok] += h @ wdT'  (atomic combine) --------------
__global__ __launch_bounds__(256) void gemm2_kernel(
    const bf16* __restrict__ h, const bf16* __restrict__ wdT,
    const int* __restrict__ off, const int* __restrict__ counts,
    const int* __restrict__ tok_list, float* __restrict__ out, int row_lo)
{
  const int m0 = row_lo + blockIdx.x * BM;
  if (m0 >= off[En]) return;
  int e = 0;
  while (off[e + 1] <= m0) ++e;
  const int base = off[e], cnt = counts[e];
  const int n0 = blockIdx.y * 128;

  __shared__ bf16 As[BM * BK];
  __shared__ bf16 Bs[128 * BK];

  const int tid = threadIdx.x;
  const int lane = tid & 63, wid = tid >> 6;
  const int wm = (wid >> 1) * 64, wn = (wid & 1) * 64;

  f32x4 z4; z4[0] = 0.f; z4[1] = 0.f; z4[2] = 0.f; z4[3] = 0.f;
  f32x4 acc[4][4];
#pragma unroll
  for (int i = 0; i < 4; ++i)
#pragma unroll
    for (int j = 0; j < 4; ++j) acc[i][j] = z4;

  const bf16* wde = wdT + (size_t)e * Cn * Fn;
  const bf16* hb  = h + (size_t)(m0 - row_lo) * Fn;

  const int srow = lane >> 2;
  const int scol = (lane & 3) * 8;
  const bf16* agp = hb  + (size_t)(wid * 32 + srow) * Fn + scol;
  const bf16* bgp = wde + (size_t)(n0 + wid * 32 + srow) * Fn + scol;
  bf16* alp = As + wid * 32 * BK + lane * 8;
  bf16* blp = Bs + wid * 32 * BK + lane * 8;

  const int fr = lane & 15, kq = (lane >> 4) * 8;

  for (int kt = 0; kt < Fn / BK; ++kt) {   // 86 iters exact
    __syncthreads();
    gload16(agp, alp);
    gload16(agp + 16 * Fn, alp + 16 * BK);
    gload16(bgp, blp);
    gload16(bgp + 16 * Fn, blp + 16 * BK);
    agp += BK; bgp += BK;
    __syncthreads();

    bf16x8 a[4], b[4];
#pragma unroll
    for (int mi = 0; mi < 4; ++mi)
      a[mi] = *(const bf16x8*)(As + (wm + mi * 16 + fr) * BK + kq);
#pragma unroll
    for (int ni = 0; ni < 4; ++ni)
      b[ni] = *(const bf16x8*)(Bs + (wn + ni * 16 + fr) * BK + kq);
#pragma unroll
    for (int mi = 0; mi < 4; ++mi)
#pragma unroll
      for (int ni = 0; ni < 4; ++ni)
        acc[mi][ni] = __builtin_amdgcn_mfma_f32_16x16x32_bf16(a[mi], b[ni], acc[mi][ni], 0, 0, 0);
  }

  const int rq = (lane >> 4) * 4, cl = lane & 15;
#pragma unroll
  for (int mi = 0; mi < 4; ++mi) {
#pragma unroll
    for (int r = 0; r < 4; ++r) {
      int grow = m0 + wm + mi * 16 + rq + r;
      if (grow - base >= cnt) continue;
      int tok = tok_list[grow];
      float* orow = out + (size_t)tok * Cn + n0;
#pragma unroll
      for (int ni = 0; ni < 4; ++ni)
        atomicAdd(orow + wn + ni * 16 + cl, acc[mi][ni][r]);
    }
  }
}

// ---------------- host launch ------------------------------------------------
extern "C" void kernel_launch(void* const* d_in, const int* in_sizes, int n_in,
                              void* d_out, int out_size, void* d_ws, size_t ws_size,
                              hipStream_t stream)
{
  const float* x     = (const float*)d_in[0];
  const float* wgate = (const float*)d_in[1];
  const float* wg    = (const float*)d_in[2];
  const float* wu    = (const float*)d_in[3];
  const float* wd    = (const float*)d_in[4];

  char* ws = (char*)d_ws;
  int* counts = (int*)ws;
  int* fill   = counts + 8;
  int* off    = fill + 8;
  size_t o = 256;
  int*   topk_i   = (int*)(ws + o);   o += (size_t)Tn * 2 * 4;
  float* topk_w   = (float*)(ws + o); o += (size_t)Tn * 2 * 4;
  int*   tok_list = (int*)(ws + o);   o += (size_t)MAXROWS * 4;
  float* wgt_list = (float*)(ws + o); o += (size_t)MAXROWS * 4;
  o = (o + 255) & ~(size_t)255;
  const size_t WSZ = (size_t)En * Fn * Cn;
  bf16* wgT = (bf16*)(ws + o); o += WSZ * 2;
  bf16* wuT = (bf16*)(ws + o); o += WSZ * 2;
  bf16* wdT = (bf16*)(ws + o); o += WSZ * 2;
  bf16* xg  = (bf16*)(ws + o); o += (size_t)MAXROWS * Cn * 2;
  bf16* h   = (bf16*)(ws + o);

  size_t havail = ws_size > o ? ws_size - o : 0;
  long crows = (long)(havail / ((size_t)Fn * 2));
  crows &= ~(long)127;
  if (crows > MAXROWS) crows = MAXROWS;
  if (crows < 128) crows = 128;
  const int chunk_rows = (int)crows;
  const int nch = (MAXROWS + chunk_rows - 1) / chunk_rows;

  hipMemsetAsync(counts, 0, 256, stream);
  hipMemsetAsync(tok_list, 0xFF, (size_t)MAXROWS * 4, stream);  // -1 = pad row
  hipMemsetAsync(d_out, 0, (size_t)out_size * sizeof(float), stream);

  transpose_cvt<<<dim3(Cn / 32, Fn / 32, En), 256, 0, stream>>>(wg, wgT, Cn, Fn);
  transpose_cvt<<<dim3(Cn / 32, Fn / 32, En), 256, 0, stream>>>(wu, wuT, Cn, Fn);
  transpose_cvt<<<dim3(Fn / 32, Cn / 32, En), 256, 0, stream>>>(wd, wdT, Fn, Cn);

  gate_kernel<<<Tn / 4, 256, 0, stream>>>(x, wgate, topk_i, topk_w, counts);
  offsets_kernel<<<1, 64, 0, stream>>>(counts, fill, off);
  scatter_kernel<<<Tn / 256, 256, 0, stream>>>(topk_i, topk_w, fill, tok_list, wgt_list);
  gather_x<<<MAXROWS, 256, 0, stream>>>(x, tok_list, xg);

  const int mt = chunk_rows / BM;
  for (int c = 0; c < nch; ++c) {
    int row_lo = c * chunk_rows;
    gemm1_kernel<<<dim3(mt, Fn / 64), 256, 0, stream>>>(
        xg, wgT, wuT, off, counts, wgt_list, h, row_lo);
    gemm2_kernel<<<dim3(mt, Cn / 128), 256, 0, stream>>>(
        h, wdT, off, counts, tok_list, d_out ? (float*)d_out : nullptr, row_lo);
  }
}

// Round 3
// 1058.839 us; speedup vs baseline: 1.7844x; 1.0587x over previous
//
#include <hip/hip_runtime.h>

#define Tn      8192
#define Cn      1024
#define En      8
#define Fn      2752
#define MAXROWS 17408
#define BM 128

typedef __bf16 bf16;
typedef bf16  bf16x8 __attribute__((ext_vector_type(8)));
typedef bf16  bf16x4 __attribute__((ext_vector_type(4)));
typedef float f32x4  __attribute__((ext_vector_type(4)));

__device__ __forceinline__ void gload16(const bf16* g, bf16* l) {
  __builtin_amdgcn_global_load_lds(
      (const __attribute__((address_space(1))) unsigned int*)g,
      (__attribute__((address_space(3))) unsigned int*)l, 16, 0, 0);
}

// ---------------- gating ------------------------------------------------------
__global__ __launch_bounds__(256) void gate_kernel(
    const float* __restrict__ x, const float* __restrict__ wgate,
    int* __restrict__ topk_i, float* __restrict__ topk_w, int* __restrict__ counts)
{
  int lane = threadIdx.x & 63;
  int wid  = threadIdx.x >> 6;
  int t = blockIdx.x * 4 + wid;
  const float* xr = x + (size_t)t * Cn;
  float acc[En];
#pragma unroll
  for (int e = 0; e < En; ++e) acc[e] = 0.f;
  for (int c = lane; c < Cn; c += 64) {
    float xv = xr[c];
#pragma unroll
    for (int e = 0; e < En; ++e) acc[e] = fmaf(xv, wgate[e * Cn + c], acc[e]);
  }
#pragma unroll
  for (int e = 0; e < En; ++e) {
#pragma unroll
    for (int o = 32; o > 0; o >>= 1) acc[e] += __shfl_xor(acc[e], o, 64);
  }
  if (lane == 0) {
    float mx = acc[0];
#pragma unroll
    for (int e = 1; e < En; ++e) mx = fmaxf(mx, acc[e]);
    float p[En], Z = 0.f;
#pragma unroll
    for (int e = 0; e < En; ++e) { p[e] = __expf(acc[e] - mx); Z += p[e]; }
    int i0 = 0;
#pragma unroll
    for (int e = 1; e < En; ++e) if (p[e] > p[i0]) i0 = e;
    int i1 = (i0 == 0) ? 1 : 0;
#pragma unroll
    for (int e = 0; e < En; ++e) if (e != i0 && p[e] > p[i1]) i1 = e;
    float s0 = p[i0] / Z, s1 = p[i1] / Z;
    float inv = 1.f / (s0 + s1 + 1e-9f);
    topk_i[2 * t] = i0;       topk_i[2 * t + 1] = i1;
    topk_w[2 * t] = s0 * inv; topk_w[2 * t + 1] = s1 * inv;
    atomicAdd(&counts[i0], 1);
    atomicAdd(&counts[i1], 1);
  }
}

__global__ void offsets_kernel(const int* __restrict__ counts,
                               int* __restrict__ fill, int* __restrict__ off)
{
  if (threadIdx.x == 0 && blockIdx.x == 0) {
    int o = 0;
    for (int e = 0; e < En; ++e) {
      off[e]  = o;
      fill[e] = o;
      o += (counts[e] + BM - 1) & ~(BM - 1);
    }
    off[En] = o;
  }
}

__global__ __launch_bounds__(256) void scatter_kernel(
    const int* __restrict__ topk_i, const float* __restrict__ topk_w,
    int* __restrict__ fill, int* __restrict__ tok_list, float* __restrict__ wgt_list)
{
  int t = blockIdx.x * 256 + threadIdx.x;
#pragma unroll
  for (int j = 0; j < 2; ++j) {
    int e = topk_i[2 * t + j];
    int pos = atomicAdd(&fill[e], 1);
    tok_list[pos] = t;
    wgt_list[pos] = topk_w[2 * t + j];
  }
}

__global__ __launch_bounds__(256) void gather_x(
    const float* __restrict__ x, const int* __restrict__ tok_list, bf16* __restrict__ xg)
{
  int row = blockIdx.x;
  int tok = tok_list[row];
  int c = threadIdx.x * 4;
  float4 v = make_float4(0.f, 0.f, 0.f, 0.f);
  if (tok >= 0) v = *(const float4*)(x + (size_t)tok * Cn + c);
  bf16x4 pv;
  pv[0] = (bf16)v.x; pv[1] = (bf16)v.y; pv[2] = (bf16)v.z; pv[3] = (bf16)v.w;
  *(bf16x4*)(xg + (size_t)row * Cn + c) = pv;
}

// ---------------- fast transpose + fp32->bf16 ---------------------------------
// src [z][M][N] fp32 -> dst [z][N][M] bf16.  64x64 tiles, vectorized both sides.
__global__ __launch_bounds__(256) void transpose_cvt(
    const float* __restrict__ src, bf16* __restrict__ dst, int M, int N)
{
  __shared__ float L[64][65];
  src += (size_t)blockIdx.z * M * N;
  dst += (size_t)blockIdx.z * M * N;
  const int bm = blockIdx.x * 64;
  const int bn = blockIdx.y * 64;
  const int tid = threadIdx.x;
  const int mr = tid >> 4, nseg = tid & 15;
#pragma unroll
  for (int p = 0; p < 4; ++p) {
    int m = p * 16 + mr;
    float4 v = *(const float4*)(src + (size_t)(bm + m) * N + bn + nseg * 4);
    L[nseg * 4 + 0][m] = v.x;
    L[nseg * 4 + 1][m] = v.y;
    L[nseg * 4 + 2][m] = v.z;
    L[nseg * 4 + 3][m] = v.w;
  }
  __syncthreads();
  const int nr = tid >> 3, mseg = tid & 7;
#pragma unroll
  for (int q = 0; q < 2; ++q) {
    int n = q * 32 + nr;
    bf16x8 w;
#pragma unroll
    for (int j = 0; j < 8; ++j) w[j] = (bf16)L[n][mseg * 8 + j];
    *(bf16x8*)(dst + (size_t)(bn + n) * M + bm + mseg * 8) = w;
  }
}

// ---------------- GEMM1: h = wgt * silu(xg@wgT') * (xg@wuT') ------------------
// 128x64 (dual gate+up), BK=64, XOR-swizzled LDS (conflict-free frag reads).
__global__ __launch_bounds__(256) void gemm1_kernel(
    const bf16* __restrict__ xg, const bf16* __restrict__ wgT, const bf16* __restrict__ wuT,
    const int* __restrict__ off, const int* __restrict__ counts,
    const float* __restrict__ wgt_list, bf16* __restrict__ h, int row_lo)
{
  const int m0 = row_lo + blockIdx.x * BM;
  if (m0 >= off[En]) return;
  int e = 0;
  while (off[e + 1] <= m0) ++e;
  const int base = off[e], cnt = counts[e];
  const int n0 = blockIdx.y * 64;

  __shared__ bf16 As[128 * 64];
  __shared__ bf16 Bg[64 * 64];
  __shared__ bf16 Bu[64 * 64];

  const int tid = threadIdx.x;
  const int lane = tid & 63, wid = tid >> 6;
  const int wm = (wid >> 1) * 64, wn = (wid & 1) * 32;
  const int fr = lane & 15, q = lane >> 4;
  const int lrow = lane >> 3;
  const int sx = ((lane & 7) ^ (lrow & 7)) * 8;   // xor-swizzled global k-seg

  f32x4 z4; z4[0] = 0.f; z4[1] = 0.f; z4[2] = 0.f; z4[3] = 0.f;
  f32x4 accg[4][2], accu[4][2];
#pragma unroll
  for (int i = 0; i < 4; ++i)
#pragma unroll
    for (int j = 0; j < 2; ++j) { accg[i][j] = z4; accu[i][j] = z4; }

  const bf16* wge = wgT + (size_t)e * Fn * Cn;
  const bf16* wue = wuT + (size_t)e * Fn * Cn;

  const bf16* agp = xg  + (size_t)(m0 + wid * 32 + lrow) * Cn + sx;
  const bf16* bgp = wge + (size_t)(n0 + wid * 16 + lrow) * Cn + sx;
  const bf16* bup = wue + (size_t)(n0 + wid * 16 + lrow) * Cn + sx;
  bf16* alp = As + wid * 32 * 64 + lane * 8;
  bf16* blg = Bg + wid * 16 * 64 + lane * 8;
  bf16* blu = Bu + wid * 16 * 64 + lane * 8;

  const int t0 = (q ^ (lane & 7)) * 8;   // slot offset kh=0 (elements)
  // kh=1 slot = t0 ^ 32

  for (int kt = 0; kt < Cn / 64; ++kt) {
    __syncthreads();
#pragma unroll
    for (int i = 0; i < 4; ++i)
      gload16(agp + (size_t)i * 8 * Cn, alp + i * 8 * 64);
#pragma unroll
    for (int i = 0; i < 2; ++i) {
      gload16(bgp + (size_t)i * 8 * Cn, blg + i * 8 * 64);
      gload16(bup + (size_t)i * 8 * Cn, blu + i * 8 * 64);
    }
    agp += 64; bgp += 64; bup += 64;
    __syncthreads();

#pragma unroll
    for (int kh = 0; kh < 2; ++kh) {
      const int tt = t0 ^ (kh * 32);
      bf16x8 a[4], bg[2], bu[2];
#pragma unroll
      for (int mi = 0; mi < 4; ++mi)
        a[mi] = *(const bf16x8*)(As + (wm + mi * 16 + fr) * 64 + tt);
#pragma unroll
      for (int ni = 0; ni < 2; ++ni) {
        bg[ni] = *(const bf16x8*)(Bg + (wn + ni * 16 + fr) * 64 + tt);
        bu[ni] = *(const bf16x8*)(Bu + (wn + ni * 16 + fr) * 64 + tt);
      }
#pragma unroll
      for (int mi = 0; mi < 4; ++mi)
#pragma unroll
        for (int ni = 0; ni < 2; ++ni) {
          accg[mi][ni] = __builtin_amdgcn_mfma_f32_16x16x32_bf16(a[mi], bg[ni], accg[mi][ni], 0, 0, 0);
          accu[mi][ni] = __builtin_amdgcn_mfma_f32_16x16x32_bf16(a[mi], bu[ni], accu[mi][ni], 0, 0, 0);
        }
    }
  }

  const int rq = (lane >> 4) * 4, cl = lane & 15;
#pragma unroll
  for (int mi = 0; mi < 4; ++mi) {
#pragma unroll
    for (int r = 0; r < 4; ++r) {
      int grow = m0 + wm + mi * 16 + rq + r;
      float w = (grow - base < cnt) ? wgt_list[grow] : 0.f;
      bf16* hr = h + (size_t)(grow - row_lo) * Fn + n0;
#pragma unroll
      for (int ni = 0; ni < 2; ++ni) {
        float g = accg[mi][ni][r], u = accu[mi][ni][r];
        float hv = w * u * (g / (1.f + __expf(-g)));
        hr[wn + ni * 16 + cl] = (bf16)hv;
      }
    }
  }
}

// ---------------- GEMM2: out[tok] += h @ wdT' (atomic combine) ---------------
// 128x128, BK=64, XOR-swizzled LDS.
__global__ __launch_bounds__(256) void gemm2_kernel(
    const bf16* __restrict__ h, const bf16* __restrict__ wdT,
    const int* __restrict__ off, const int* __restrict__ counts,
    const int* __restrict__ tok_list, float* __restrict__ out, int row_lo)
{
  const int m0 = row_lo + blockIdx.x * BM;
  if (m0 >= off[En]) return;
  int e = 0;
  while (off[e + 1] <= m0) ++e;
  const int base = off[e], cnt = counts[e];
  const int n0 = blockIdx.y * 128;

  __shared__ bf16 As[128 * 64];
  __shared__ bf16 Bs[128 * 64];

  const int tid = threadIdx.x;
  const int lane = tid & 63, wid = tid >> 6;
  const int wm = (wid >> 1) * 64, wn = (wid & 1) * 64;
  const int fr = lane & 15, q = lane >> 4;
  const int lrow = lane >> 3;
  const int sx = ((lane & 7) ^ (lrow & 7)) * 8;

  f32x4 z4; z4[0] = 0.f; z4[1] = 0.f; z4[2] = 0.f; z4[3] = 0.f;
  f32x4 acc[4][4];
#pragma unroll
  for (int i = 0; i < 4; ++i)
#pragma unroll
    for (int j = 0; j < 4; ++j) acc[i][j] = z4;

  const bf16* wde = wdT + (size_t)e * Cn * Fn;
  const bf16* hb  = h + (size_t)(m0 - row_lo) * Fn;

  const bf16* agp = hb  + (size_t)(wid * 32 + lrow) * Fn + sx;
  const bf16* bgp = wde + (size_t)(n0 + wid * 32 + lrow) * Fn + sx;
  bf16* alp = As + wid * 32 * 64 + lane * 8;
  bf16* blp = Bs + wid * 32 * 64 + lane * 8;

  const int t0 = (q ^ (lane & 7)) * 8;

  for (int kt = 0; kt < Fn / 64; ++kt) {   // 43 iters exact
    __syncthreads();
#pragma unroll
    for (int i = 0; i < 4; ++i) {
      gload16(agp + (size_t)i * 8 * Fn, alp + i * 8 * 64);
      gload16(bgp + (size_t)i * 8 * Fn, blp + i * 8 * 64);
    }
    agp += 64; bgp += 64;
    __syncthreads();

#pragma unroll
    for (int kh = 0; kh < 2; ++kh) {
      const int tt = t0 ^ (kh * 32);
      bf16x8 a[4], b[4];
#pragma unroll
      for (int mi = 0; mi < 4; ++mi)
        a[mi] = *(const bf16x8*)(As + (wm + mi * 16 + fr) * 64 + tt);
#pragma unroll
      for (int ni = 0; ni < 4; ++ni)
        b[ni] = *(const bf16x8*)(Bs + (wn + ni * 16 + fr) * 64 + tt);
#pragma unroll
      for (int mi = 0; mi < 4; ++mi)
#pragma unroll
        for (int ni = 0; ni < 4; ++ni)
          acc[mi][ni] = __builtin_amdgcn_mfma_f32_16x16x32_bf16(a[mi], b[ni], acc[mi][ni], 0, 0, 0);
    }
  }

  const int rq = (lane >> 4) * 4, cl = lane & 15;
#pragma unroll
  for (int mi = 0; mi < 4; ++mi) {
#pragma unroll
    for (int r = 0; r < 4; ++r) {
      int grow = m0 + wm + mi * 16 + rq + r;
      if (grow - base >= cnt) continue;
      int tok = tok_list[grow];
      float* orow = out + (size_t)tok * Cn + n0;
#pragma unroll
      for (int ni = 0; ni < 4; ++ni)
        atomicAdd(orow + wn + ni * 16 + cl, acc[mi][ni][r]);
    }
  }
}

// ---------------- host launch ------------------------------------------------
extern "C" void kernel_launch(void* const* d_in, const int* in_sizes, int n_in,
                              void* d_out, int out_size, void* d_ws, size_t ws_size,
                              hipStream_t stream)
{
  const float* x     = (const float*)d_in[0];
  const float* wgate = (const float*)d_in[1];
  const float* wg    = (const float*)d_in[2];
  const float* wu    = (const float*)d_in[3];
  const float* wd    = (const float*)d_in[4];

  char* ws = (char*)d_ws;
  int* counts = (int*)ws;
  int* fill   = counts + 8;
  int* off    = fill + 8;
  size_t o = 256;
  int*   topk_i   = (int*)(ws + o);   o += (size_t)Tn * 2 * 4;
  float* topk_w   = (float*)(ws + o); o += (size_t)Tn * 2 * 4;
  int*   tok_list = (int*)(ws + o);   o += (size_t)MAXROWS * 4;
  float* wgt_list = (float*)(ws + o); o += (size_t)MAXROWS * 4;
  o = (o + 255) & ~(size_t)255;
  const size_t WSZ = (size_t)En * Fn * Cn;
  bf16* wgT = (bf16*)(ws + o); o += WSZ * 2;
  bf16* wuT = (bf16*)(ws + o); o += WSZ * 2;
  bf16* wdT = (bf16*)(ws + o); o += WSZ * 2;
  bf16* xg  = (bf16*)(ws + o); o += (size_t)MAXROWS * Cn * 2;
  bf16* h   = (bf16*)(ws + o);

  size_t havail = ws_size > o ? ws_size - o : 0;
  long crows = (long)(havail / ((size_t)Fn * 2));
  crows &= ~(long)127;
  if (crows > MAXROWS) crows = MAXROWS;
  if (crows < 128) crows = 128;
  const int chunk_rows = (int)crows;
  const int nch = (MAXROWS + chunk_rows - 1) / chunk_rows;

  hipMemsetAsync(counts, 0, 256, stream);
  hipMemsetAsync(tok_list, 0xFF, (size_t)MAXROWS * 4, stream);
  hipMemsetAsync(d_out, 0, (size_t)out_size * sizeof(float), stream);

  transpose_cvt<<<dim3(Cn / 64, Fn / 64, En), 256, 0, stream>>>(wg, wgT, Cn, Fn);
  transpose_cvt<<<dim3(Cn / 64, Fn / 64, En), 256, 0, stream>>>(wu, wuT, Cn, Fn);
  transpose_cvt<<<dim3(Fn / 64, Cn / 64, En), 256, 0, stream>>>(wd, wdT, Fn, Cn);

  gate_kernel<<<Tn / 4, 256, 0, stream>>>(x, wgate, topk_i, topk_w, counts);
  offsets_kernel<<<1, 64, 0, stream>>>(counts, fill, off);
  scatter_kernel<<<Tn / 256, 256, 0, stream>>>(topk_i, topk_w, fill, tok_list, wgt_list);
  gather_x<<<MAXROWS, 256, 0, stream>>>(x, tok_list, xg);

  const int mt = chunk_rows / BM;
  for (int c = 0; c < nch; ++c) {
    int row_lo = c * chunk_rows;
    gemm1_kernel<<<dim3(mt, Fn / 64), 256, 0, stream>>>(
        xg, wgT, wuT, off, counts, wgt_list, h, row_lo);
    gemm2_kernel<<<dim3(mt, Cn / 128), 256, 0, stream>>>(
        h, wdT, off, counts, tok_list, (float*)d_out, row_lo);
  }
}

// Round 4
// 1022.926 us; speedup vs baseline: 1.8470x; 1.0351x over previous
//
#include <hip/hip_runtime.h>

#define Tn      8192
#define Cn      1024
#define En      8
#define Fn      2752
#define MAXROWS 17408
#define BM 128

typedef __bf16 bf16;
typedef bf16  bf16x8 __attribute__((ext_vector_type(8)));
typedef bf16  bf16x4 __attribute__((ext_vector_type(4)));
typedef float f32x4  __attribute__((ext_vector_type(4)));

__device__ __forceinline__ void gload16(const bf16* g, bf16* l) {
  __builtin_amdgcn_global_load_lds(
      (const __attribute__((address_space(1))) unsigned int*)g,
      (__attribute__((address_space(3))) unsigned int*)l, 16, 0, 0);
}

// ---------------- gating ------------------------------------------------------
__global__ __launch_bounds__(256) void gate_kernel(
    const float* __restrict__ x, const float* __restrict__ wgate,
    int* __restrict__ topk_i, float* __restrict__ topk_w, int* __restrict__ counts)
{
  int lane = threadIdx.x & 63;
  int wid  = threadIdx.x >> 6;
  int t = blockIdx.x * 4 + wid;
  const float* xr = x + (size_t)t * Cn;
  float acc[En];
#pragma unroll
  for (int e = 0; e < En; ++e) acc[e] = 0.f;
  for (int c = lane; c < Cn; c += 64) {
    float xv = xr[c];
#pragma unroll
    for (int e = 0; e < En; ++e) acc[e] = fmaf(xv, wgate[e * Cn + c], acc[e]);
  }
#pragma unroll
  for (int e = 0; e < En; ++e) {
#pragma unroll
    for (int o = 32; o > 0; o >>= 1) acc[e] += __shfl_xor(acc[e], o, 64);
  }
  if (lane == 0) {
    float mx = acc[0];
#pragma unroll
    for (int e = 1; e < En; ++e) mx = fmaxf(mx, acc[e]);
    float p[En], Z = 0.f;
#pragma unroll
    for (int e = 0; e < En; ++e) { p[e] = __expf(acc[e] - mx); Z += p[e]; }
    int i0 = 0;
#pragma unroll
    for (int e = 1; e < En; ++e) if (p[e] > p[i0]) i0 = e;
    int i1 = (i0 == 0) ? 1 : 0;
#pragma unroll
    for (int e = 0; e < En; ++e) if (e != i0 && p[e] > p[i1]) i1 = e;
    float s0 = p[i0] / Z, s1 = p[i1] / Z;
    float inv = 1.f / (s0 + s1 + 1e-9f);
    topk_i[2 * t] = i0;       topk_i[2 * t + 1] = i1;
    topk_w[2 * t] = s0 * inv; topk_w[2 * t + 1] = s1 * inv;
    atomicAdd(&counts[i0], 1);
    atomicAdd(&counts[i1], 1);
  }
}

__global__ void offsets_kernel(const int* __restrict__ counts,
                               int* __restrict__ fill, int* __restrict__ off)
{
  if (threadIdx.x == 0 && blockIdx.x == 0) {
    int o = 0;
    for (int e = 0; e < En; ++e) {
      off[e]  = o;
      fill[e] = o;
      o += (counts[e] + BM - 1) & ~(BM - 1);
    }
    off[En] = o;
  }
}

// scatter: also records inverse map token -> its 2 rows (for atomic-free combine)
__global__ __launch_bounds__(256) void scatter_kernel(
    const int* __restrict__ topk_i, const float* __restrict__ topk_w,
    int* __restrict__ fill, int* __restrict__ tok_list, float* __restrict__ wgt_list,
    int* __restrict__ inv_rows)
{
  int t = blockIdx.x * 256 + threadIdx.x;
#pragma unroll
  for (int j = 0; j < 2; ++j) {
    int e = topk_i[2 * t + j];
    int pos = atomicAdd(&fill[e], 1);
    tok_list[pos] = t;
    wgt_list[pos] = topk_w[2 * t + j];
    inv_rows[2 * t + j] = pos;
  }
}

__global__ __launch_bounds__(256) void gather_x(
    const float* __restrict__ x, const int* __restrict__ tok_list, bf16* __restrict__ xg)
{
  int row = blockIdx.x;
  int tok = tok_list[row];
  int c = threadIdx.x * 4;
  float4 v = make_float4(0.f, 0.f, 0.f, 0.f);
  if (tok >= 0) v = *(const float4*)(x + (size_t)tok * Cn + c);
  bf16x4 pv;
  pv[0] = (bf16)v.x; pv[1] = (bf16)v.y; pv[2] = (bf16)v.z; pv[3] = (bf16)v.w;
  *(bf16x4*)(xg + (size_t)row * Cn + c) = pv;
}

// ---------------- fast transpose + fp32->bf16 ---------------------------------
__global__ __launch_bounds__(256) void transpose_cvt(
    const float* __restrict__ src, bf16* __restrict__ dst, int M, int N)
{
  __shared__ float L[64][65];
  src += (size_t)blockIdx.z * M * N;
  dst += (size_t)blockIdx.z * M * N;
  const int bm = blockIdx.x * 64;
  const int bn = blockIdx.y * 64;
  const int tid = threadIdx.x;
  const int mr = tid >> 4, nseg = tid & 15;
#pragma unroll
  for (int p = 0; p < 4; ++p) {
    int m = p * 16 + mr;
    float4 v = *(const float4*)(src + (size_t)(bm + m) * N + bn + nseg * 4);
    L[nseg * 4 + 0][m] = v.x;
    L[nseg * 4 + 1][m] = v.y;
    L[nseg * 4 + 2][m] = v.z;
    L[nseg * 4 + 3][m] = v.w;
  }
  __syncthreads();
  const int nr = tid >> 3, mseg = tid & 7;
#pragma unroll
  for (int q = 0; q < 2; ++q) {
    int n = q * 32 + nr;
    bf16x8 w;
#pragma unroll
    for (int j = 0; j < 8; ++j) w[j] = (bf16)L[n][mseg * 8 + j];
    *(bf16x8*)(dst + (size_t)(bn + n) * M + bm + mseg * 8) = w;
  }
}

// LDS tile layout (BK=32, 64B rows = 4 x 16B slots):
//   LDS[row][slot] = G[row][slot ^ ((row>>1)&3)]   -> conflict-free b128 frag reads
// staging lane: row = lane>>2, gseg = (lane&3) ^ ((lane>>3)&3)
// frag read:   slot = q ^ ((fr>>1)&3),  q = lane>>4, fr = lane&15

// ---------------- GEMM1: h = wgt * silu(xg@wgT') * (xg@wuT') ------------------
// 128 x 64 (dual gate+up), BK=32, grid: x = n (fast), y = m.
__global__ __launch_bounds__(256) void gemm1_kernel(
    const bf16* __restrict__ xg, const bf16* __restrict__ wgT, const bf16* __restrict__ wuT,
    const int* __restrict__ off, const int* __restrict__ counts,
    const float* __restrict__ wgt_list, bf16* __restrict__ h, int row_lo)
{
  const int m0 = row_lo + blockIdx.y * BM;
  if (m0 >= off[En]) return;
  int e = 0;
  while (off[e + 1] <= m0) ++e;
  const int base = off[e], cnt = counts[e];
  const int n0 = blockIdx.x * 64;

  __shared__ bf16 As[128 * 32];
  __shared__ bf16 Bg[64 * 32];
  __shared__ bf16 Bu[64 * 32];

  const int tid = threadIdx.x;
  const int lane = tid & 63, wid = tid >> 6;
  const int wm = (wid >> 1) * 64, wn = (wid & 1) * 32;
  const int fr = lane & 15, q = lane >> 4;
  const int gseg = (lane & 3) ^ ((lane >> 3) & 3);
  const int lrow = lane >> 2;

  f32x4 z4; z4[0] = 0.f; z4[1] = 0.f; z4[2] = 0.f; z4[3] = 0.f;
  f32x4 accg[4][2], accu[4][2];
#pragma unroll
  for (int i = 0; i < 4; ++i)
#pragma unroll
    for (int j = 0; j < 2; ++j) { accg[i][j] = z4; accu[i][j] = z4; }

  const bf16* wge = wgT + (size_t)e * Fn * Cn;
  const bf16* wue = wuT + (size_t)e * Fn * Cn;

  const bf16* agp = xg  + (size_t)(m0 + wid * 32 + lrow) * Cn + gseg * 8;
  const bf16* bgp = wge + (size_t)(n0 + wid * 16 + lrow) * Cn + gseg * 8;
  const bf16* bup = wue + (size_t)(n0 + wid * 16 + lrow) * Cn + gseg * 8;
  bf16* alp = As + wid * 32 * 32 + lane * 8;
  bf16* blg = Bg + wid * 16 * 32 + lane * 8;
  bf16* blu = Bu + wid * 16 * 32 + lane * 8;

  const int tt = (q ^ ((fr >> 1) & 3)) * 8;   // swizzled frag slot (elements)

  for (int kt = 0; kt < Cn / 32; ++kt) {
    __syncthreads();
    gload16(agp, alp);
    gload16(agp + (size_t)16 * Cn, alp + 16 * 32);
    gload16(bgp, blg);
    gload16(bup, blu);
    agp += 32; bgp += 32; bup += 32;
    __syncthreads();

    bf16x8 a[4], bg[2], bu[2];
#pragma unroll
    for (int mi = 0; mi < 4; ++mi)
      a[mi] = *(const bf16x8*)(As + (wm + mi * 16 + fr) * 32 + tt);
#pragma unroll
    for (int ni = 0; ni < 2; ++ni) {
      bg[ni] = *(const bf16x8*)(Bg + (wn + ni * 16 + fr) * 32 + tt);
      bu[ni] = *(const bf16x8*)(Bu + (wn + ni * 16 + fr) * 32 + tt);
    }
#pragma unroll
    for (int mi = 0; mi < 4; ++mi)
#pragma unroll
      for (int ni = 0; ni < 2; ++ni) {
        accg[mi][ni] = __builtin_amdgcn_mfma_f32_16x16x32_bf16(a[mi], bg[ni], accg[mi][ni], 0, 0, 0);
        accu[mi][ni] = __builtin_amdgcn_mfma_f32_16x16x32_bf16(a[mi], bu[ni], accu[mi][ni], 0, 0, 0);
      }
  }

  const int rq = (lane >> 4) * 4, cl = lane & 15;
#pragma unroll
  for (int mi = 0; mi < 4; ++mi) {
#pragma unroll
    for (int r = 0; r < 4; ++r) {
      int grow = m0 + wm + mi * 16 + rq + r;
      float w = (grow - base < cnt) ? wgt_list[grow] : 0.f;
      bf16* hr = h + (size_t)(grow - row_lo) * Fn + n0;
#pragma unroll
      for (int ni = 0; ni < 2; ++ni) {
        float g = accg[mi][ni][r], u = accu[mi][ni][r];
        float hv = w * u * (g / (1.f + __expf(-g)));
        hr[wn + ni * 16 + cl] = (bf16)hv;
      }
    }
  }
}

// ---------------- GEMM2: h2[row] = h[row] @ wdT'  (no atomics) ----------------
// 128 x 128, BK=32, grid: x = n (8, fast), y = m.
__global__ __launch_bounds__(256) void gemm2_kernel(
    const bf16* __restrict__ h, const bf16* __restrict__ wdT,
    const int* __restrict__ off, bf16* __restrict__ h2, int row_lo)
{
  const int m0 = row_lo + blockIdx.y * BM;
  if (m0 >= off[En]) return;
  int e = 0;
  while (off[e + 1] <= m0) ++e;
  const int n0 = blockIdx.x * 128;

  __shared__ bf16 As[128 * 32];
  __shared__ bf16 Bs[128 * 32];

  const int tid = threadIdx.x;
  const int lane = tid & 63, wid = tid >> 6;
  const int wm = (wid >> 1) * 64, wn = (wid & 1) * 64;
  const int fr = lane & 15, q = lane >> 4;
  const int gseg = (lane & 3) ^ ((lane >> 3) & 3);
  const int lrow = lane >> 2;

  f32x4 z4; z4[0] = 0.f; z4[1] = 0.f; z4[2] = 0.f; z4[3] = 0.f;
  f32x4 acc[4][4];
#pragma unroll
  for (int i = 0; i < 4; ++i)
#pragma unroll
    for (int j = 0; j < 4; ++j) acc[i][j] = z4;

  const bf16* wde = wdT + (size_t)e * Cn * Fn;
  const bf16* hb  = h + (size_t)(m0 - row_lo) * Fn;

  const bf16* agp = hb  + (size_t)(wid * 32 + lrow) * Fn + gseg * 8;
  const bf16* bgp = wde + (size_t)(n0 + wid * 32 + lrow) * Fn + gseg * 8;
  bf16* alp = As + wid * 32 * 32 + lane * 8;
  bf16* blp = Bs + wid * 32 * 32 + lane * 8;

  const int tt = (q ^ ((fr >> 1) & 3)) * 8;

  for (int kt = 0; kt < Fn / 32; ++kt) {   // 86 iters exact
    __syncthreads();
    gload16(agp, alp);
    gload16(agp + (size_t)16 * Fn, alp + 16 * 32);
    gload16(bgp, blp);
    gload16(bgp + (size_t)16 * Fn, blp + 16 * 32);
    agp += 32; bgp += 32;
    __syncthreads();

    bf16x8 a[4], b[4];
#pragma unroll
    for (int mi = 0; mi < 4; ++mi)
      a[mi] = *(const bf16x8*)(As + (wm + mi * 16 + fr) * 32 + tt);
#pragma unroll
    for (int ni = 0; ni < 4; ++ni)
      b[ni] = *(const bf16x8*)(Bs + (wn + ni * 16 + fr) * 32 + tt);
#pragma unroll
    for (int mi = 0; mi < 4; ++mi)
#pragma unroll
      for (int ni = 0; ni < 4; ++ni)
        acc[mi][ni] = __builtin_amdgcn_mfma_f32_16x16x32_bf16(a[mi], b[ni], acc[mi][ni], 0, 0, 0);
  }

  const int rq = (lane >> 4) * 4, cl = lane & 15;
#pragma unroll
  for (int mi = 0; mi < 4; ++mi) {
#pragma unroll
    for (int r = 0; r < 4; ++r) {
      int grow = m0 + wm + mi * 16 + rq + r;
      bf16* orow = h2 + (size_t)grow * Cn + n0;
#pragma unroll
      for (int ni = 0; ni < 4; ++ni)
        orow[wn + ni * 16 + cl] = (bf16)acc[mi][ni][r];
    }
  }
}

// ---------------- combine: out[t] = h2[r0(t)] + h2[r1(t)] ---------------------
__global__ __launch_bounds__(256) void combine_kernel(
    const bf16* __restrict__ h2, const int* __restrict__ inv_rows,
    float* __restrict__ out)
{
  int t = blockIdx.x;
  int r0 = inv_rows[2 * t], r1 = inv_rows[2 * t + 1];
  int c = threadIdx.x * 4;
  bf16x4 a = *(const bf16x4*)(h2 + (size_t)r0 * Cn + c);
  bf16x4 b = *(const bf16x4*)(h2 + (size_t)r1 * Cn + c);
  float4 v;
  v.x = (float)a[0] + (float)b[0];
  v.y = (float)a[1] + (float)b[1];
  v.z = (float)a[2] + (float)b[2];
  v.w = (float)a[3] + (float)b[3];
  *(float4*)(out + (size_t)t * Cn + c) = v;
}

// ---------------- host launch ------------------------------------------------
extern "C" void kernel_launch(void* const* d_in, const int* in_sizes, int n_in,
                              void* d_out, int out_size, void* d_ws, size_t ws_size,
                              hipStream_t stream)
{
  const float* x     = (const float*)d_in[0];
  const float* wgate = (const float*)d_in[1];
  const float* wg    = (const float*)d_in[2];
  const float* wu    = (const float*)d_in[3];
  const float* wd    = (const float*)d_in[4];

  char* ws = (char*)d_ws;
  int* counts = (int*)ws;
  int* fill   = counts + 8;
  int* off    = fill + 8;
  size_t o = 256;
  int*   topk_i   = (int*)(ws + o);   o += (size_t)Tn * 2 * 4;
  float* topk_w   = (float*)(ws + o); o += (size_t)Tn * 2 * 4;
  int*   tok_list = (int*)(ws + o);   o += (size_t)MAXROWS * 4;
  float* wgt_list = (float*)(ws + o); o += (size_t)MAXROWS * 4;
  int*   inv_rows = (int*)(ws + o);   o += (size_t)Tn * 2 * 4;
  o = (o + 255) & ~(size_t)255;
  const size_t WSZ = (size_t)En * Fn * Cn;
  bf16* wgT = (bf16*)(ws + o); o += WSZ * 2;
  bf16* wuT = (bf16*)(ws + o); o += WSZ * 2;
  bf16* wdT = (bf16*)(ws + o); o += WSZ * 2;
  bf16* xg  = (bf16*)(ws + o); o += (size_t)MAXROWS * Cn * 2;
  bf16* h2  = (bf16*)(ws + o); o += (size_t)MAXROWS * Cn * 2;
  bf16* h   = (bf16*)(ws + o);

  size_t havail = ws_size > o ? ws_size - o : 0;
  long crows = (long)(havail / ((size_t)Fn * 2));
  crows &= ~(long)127;
  if (crows > MAXROWS) crows = MAXROWS;
  if (crows < 128) crows = 128;
  const int chunk_rows = (int)crows;
  const int nch = (MAXROWS + chunk_rows - 1) / chunk_rows;

  hipMemsetAsync(counts, 0, 256, stream);
  hipMemsetAsync(tok_list, 0xFF, (size_t)MAXROWS * 4, stream);

  transpose_cvt<<<dim3(Cn / 64, Fn / 64, En), 256, 0, stream>>>(wg, wgT, Cn, Fn);
  transpose_cvt<<<dim3(Cn / 64, Fn / 64, En), 256, 0, stream>>>(wu, wuT, Cn, Fn);
  transpose_cvt<<<dim3(Fn / 64, Cn / 64, En), 256, 0, stream>>>(wd, wdT, Fn, Cn);

  gate_kernel<<<Tn / 4, 256, 0, stream>>>(x, wgate, topk_i, topk_w, counts);
  offsets_kernel<<<1, 64, 0, stream>>>(counts, fill, off);
  scatter_kernel<<<Tn / 256, 256, 0, stream>>>(topk_i, topk_w, fill, tok_list, wgt_list, inv_rows);
  gather_x<<<MAXROWS, 256, 0, stream>>>(x, tok_list, xg);

  const int mt = chunk_rows / BM;
  for (int c = 0; c < nch; ++c) {
    int row_lo = c * chunk_rows;
    gemm1_kernel<<<dim3(Fn / 64, mt), 256, 0, stream>>>(
        xg, wgT, wuT, off, counts, wgt_list, h, row_lo);
    gemm2_kernel<<<dim3(Cn / 128, mt), 256, 0, stream>>>(
        h, wdT, off, h2, row_lo);
  }
  combine_kernel<<<Tn, 256, 0, stream>>>(h2, inv_rows, (float*)d_out);
}